// Round 1
// 233.772 us; speedup vs baseline: 1.0952x; 1.0952x over previous
//
#include <hip/hip_runtime.h>
#include <hip/hip_bf16.h>
#include <stdint.h>

typedef float f32x4 __attribute__((ext_vector_type(4)));
typedef _Float16 half8 __attribute__((ext_vector_type(8)));

#define B_ 4096
#define T_ 256
#define D_ 18
#define H_ 32
#define GK 8192   // T_*H_
#define GN 512
#define KSPLIT 4
#define SLOT 520  // hist ring slot stride in halves (16*32 + 8 pad)

// ---------- helpers ----------
__device__ __forceinline__ float fsig(float x) {
  float e = __builtin_amdgcn_exp2f(-1.442695041f * x);
  return __builtin_amdgcn_rcpf(1.0f + e);
}
// Barrier draining ONLY LDS (lgkmcnt) — global loads/stores stay in flight.
__device__ __forceinline__ void ldsbar() {
  asm volatile("s_waitcnt lgkmcnt(0)\n\ts_barrier" ::: "memory");
}

// ---------- kernel 1: W1 fp32 -> fp16 (RNE) ----------
__global__ __launch_bounds__(256) void cvtw1_kernel(const float* __restrict__ w1,
                                                    unsigned short* __restrict__ dst) {
  int i = blockIdx.x * 256 + threadIdx.x;  // float4 index, total 1048576
  float4 v = ((const float4*)w1)[i];
  unsigned short a = __builtin_bit_cast(unsigned short, (_Float16)v.x);
  unsigned short b = __builtin_bit_cast(unsigned short, (_Float16)v.y);
  unsigned short c = __builtin_bit_cast(unsigned short, (_Float16)v.z);
  unsigned short d = __builtin_bit_cast(unsigned short, (_Float16)v.w);
  uint2 o; o.x = (unsigned)a | ((unsigned)b << 16); o.y = (unsigned)c | ((unsigned)d << 16);
  ((uint2*)dst)[i] = o;
}

// ---------- kernel 2: MFMA LSTM ----------
// Block = 512 thr (8 waves) owns 16 batch elems. Wave w: tile-rows m =
// hl*4+gate, h_row = w*4+hl, orig W row = gate*32 + w*4 + hl. C layout
// row=lq*4+reg, col=lr: lane (lq,lr) gets (i,f,g,o) of h_row=w*4+lq, elem lr.
//
// R7 changes (scheduling-only + 2 algebraic rcp merges):
//  * all 8 x-fragments of a window preloaded to regs (xq[8]) -> no per-step
//    xf ds_read on the critical path
//  * acc_x(t+1) = mfma(wx,xq[t+1],bias) computed one step AHEAD (ax0/ax1
//    double buffer) -> per-step chain is read hf -> 1 mfma -> act -> write
//  * hist ring = 16 slots (2 windows): flush of window k runs inside window
//    k+1, XSTORE mid-window -> only 8 barriers per 8 steps (was 9)
//  * i*g and o*tanh(c) share one rcp each: 8 trans/h instead of 10
__global__ __launch_bounds__(512) void lstm_kernel(
    const float* __restrict__ batch, const float* __restrict__ W_ih,
    const float* __restrict__ W_hh, const float* __restrict__ b_ih,
    const float* __restrict__ b_hh, _Float16* __restrict__ hs) {
  __shared__ _Float16 hist[16 * SLOT];
  __shared__ _Float16 xs[2 * 4096];  // [buf][t(8)][elem(16) x k(32)]

  const int tid = (int)threadIdx.x;
  const int lane = tid & 63;
  const int w = tid >> 6;
  const int lq = lane >> 4;
  const int lr = lane & 15;
  const int b0 = (int)blockIdx.x * 16;

  // constant A-fragments
  half8 wx, wh;
  {
    int grow = (lr & 3) * 32 + w * 4 + (lr >> 2);
#pragma unroll
    for (int j = 0; j < 8; ++j) {
      int k = lq * 8 + j;
      wx[j] = (k < D_) ? (_Float16)W_ih[grow * D_ + k] : (_Float16)0.0f;
      wh[j] = (_Float16)W_hh[grow * H_ + k];
    }
  }
  f32x4 bias4;
#pragma unroll
  for (int r = 0; r < 4; ++r) {
    int g = r * 32 + w * 4 + lq;
    bias4[r] = b_ih[g] + b_hh[g];
  }

  // fragment-read offset (row = elem, 32-half rows, chunk-swizzled)
  const int rdo = lr * 32 + ((lq ^ ((lr >> 1) & 3)) << 3);
  const int kcol = w * 4 + lq;
  const int wro = lr * 32 + ((((kcol >> 3) ^ ((lr >> 1) & 3))) << 3) + (kcol & 7);

  // flush mapping (ring -> hs, coalesced 16B/lane)
  const int fe = tid >> 5;
  const int fs = (tid >> 2) & 7;
  const int fg = tid & 3;
  const int fl_rd = fs * SLOT + fe * 32 + ((fg ^ ((fe >> 1) & 3)) << 3);
  _Float16* fl_wp = hs + (size_t)(b0 + fe) * GK + fs * H_ + fg * 8;

  // x slab staging: 576 float4 per 8t; thread -> (elem e, q-th float4 of 36)
  const int e0 = tid / 36, q0 = tid - e0 * 36;
  const int i1 = tid + 512;
  const int e1 = i1 / 36, q1 = i1 - e1 * 36;  // only tid<64
  const float* xld0 = batch + (size_t)(b0 + e0) * (T_ * D_) + q0 * 4;
  const float* xld1 = batch + (size_t)(b0 + e1) * (T_ * D_) + q1 * 4;
  float4 xv0, xv1;

#define XLOAD(tb)                                                              \
  do {                                                                         \
    xv0 = *(const float4*)(xld0 + (tb) * 144);                                 \
    if (tid < 64) xv1 = *(const float4*)(xld1 + (tb) * 144);                   \
  } while (0)

#define XPUT(E, Q, V, buf)                                                     \
  do {                                                                         \
    int swz_ = ((E) >> 1) & 3;                                                 \
    _Pragma("unroll") for (int j = 0; j < 4; ++j) {                            \
      int f_ = (Q) * 4 + j;                                                    \
      int to_ = (f_ * 57) >> 10; /* f/18 for f<1024 */                         \
      int d_ = f_ - to_ * 18;                                                  \
      float val_ = (j == 0) ? (V).x : (j == 1) ? (V).y : (j == 2) ? (V).z : (V).w; \
      xs[(buf) * 4096 + to_ * 512 + (E) * 32 + (((d_ >> 3) ^ swz_) << 3) + (d_ & 7)] = \
          (_Float16)val_;                                                      \
    }                                                                          \
  } while (0)

#define XSTORE(buf)                                                            \
  do {                                                                         \
    XPUT(e0, q0, xv0, buf);                                                    \
    if (tid < 64) XPUT(e1, q1, xv1, buf);                                      \
  } while (0)

// step tt (0..7) of window parity p: h(t-1) from ring; AXC holds
// bias + Wih*x(t) (precomputed); PRE computes next step's ax.
#define STEP(tt, AXC, PRE)                                                     \
  do {                                                                         \
    _Float16* hrd = ((tt) == 0 ? po + 7 * SLOT : pr + ((tt)-1) * SLOT);        \
    half8 hf = *(const half8*)&hrd[rdo];                                       \
    f32x4 acc = __builtin_amdgcn_mfma_f32_16x16x32_f16(wh, hf, AXC, 0, 0, 0);  \
    PRE;                                                                       \
    float ei = __builtin_amdgcn_exp2f(-1.442695041f * acc[0]);                 \
    float eg = __builtin_amdgcn_exp2f(-2.885390082f * acc[2]);                 \
    float ig = (1.0f - eg) *                                                   \
               __builtin_amdgcn_rcpf((1.0f + ei) * (1.0f + eg));               \
    float fv = fsig(acc[1]);                                                   \
    c = fmaf(fv, c, ig);                                                       \
    float eo = __builtin_amdgcn_exp2f(-1.442695041f * acc[3]);                 \
    float ec = __builtin_amdgcn_exp2f(-2.885390082f * c);                      \
    float h = (1.0f - ec) *                                                    \
              __builtin_amdgcn_rcpf((1.0f + eo) * (1.0f + ec));                \
    pr[(tt)*SLOT + wro] = (_Float16)h;                                         \
    ldsbar();                                                                  \
  } while (0)

  XLOAD(0);  // loads fly while we zero LDS
  for (int i = tid; i < 16 * SLOT; i += 512) hist[i] = (_Float16)0.0f;
  for (int i = tid; i < 8192; i += 512) xs[i] = (_Float16)0.0f;
  ldsbar();
  XSTORE(0);   // one-time vmcnt wait
  XLOAD(1);
  ldsbar();

  float c = 0.0f;
  for (int blk = 0; blk < 32; ++blk) {
    const int p = blk & 1;
    _Float16* pr = hist + p * (8 * SLOT);
    _Float16* po = hist + (p ^ 1) * (8 * SLOT);
    const int xo = p * 4096;

    // preload the whole window's x fragments into registers
    half8 xq[8];
#pragma unroll
    for (int j = 0; j < 8; ++j) xq[j] = *(const half8*)&xs[xo + j * 512 + rdo];
    f32x4 ax0, ax1;
    ax0 = __builtin_amdgcn_mfma_f32_16x16x32_f16(wx, xq[0], bias4, 0, 0, 0);

    STEP(0, ax0, ax1 = __builtin_amdgcn_mfma_f32_16x16x32_f16(wx, xq[1], bias4, 0, 0, 0));
    STEP(1, ax1, ax0 = __builtin_amdgcn_mfma_f32_16x16x32_f16(wx, xq[2], bias4, 0, 0, 0));
    STEP(2, ax0, ax1 = __builtin_amdgcn_mfma_f32_16x16x32_f16(wx, xq[3], bias4, 0, 0, 0));
    STEP(3, ax1, ax0 = __builtin_amdgcn_mfma_f32_16x16x32_f16(wx, xq[4], bias4, 0, 0, 0));
    // stage next slab mid-window (vmcnt: loads issued a full window ago)
    if (blk < 31) XSTORE(p ^ 1);
    if (blk < 30) XLOAD(blk + 2);
    STEP(4, ax0, ax1 = __builtin_amdgcn_mfma_f32_16x16x32_f16(wx, xq[5], bias4, 0, 0, 0));
    // flush PREVIOUS window's ring half -> global (no barrier needed: it
    // lives in the other ring parity, untouched this window)
    if (blk) {
      half8 hv = *(const half8*)&hist[(p ^ 1) * (8 * SLOT) + fl_rd];
      *(half8*)(fl_wp + (size_t)(blk - 1) * (8 * H_)) = hv;
    }
    STEP(5, ax1, ax0 = __builtin_amdgcn_mfma_f32_16x16x32_f16(wx, xq[6], bias4, 0, 0, 0));
    STEP(6, ax0, ax1 = __builtin_amdgcn_mfma_f32_16x16x32_f16(wx, xq[7], bias4, 0, 0, 0));
    STEP(7, ax1, );
  }
  // final flush (window 31, parity 1)
  {
    half8 hv = *(const half8*)&hist[8 * SLOT + fl_rd];
    *(half8*)(fl_wp + (size_t)31 * (8 * H_)) = hv;
  }
#undef STEP
#undef XSTORE
#undef XPUT
#undef XLOAD
}

// ---------- kernel 3: fp16 MFMA GEMM, BM=BN=128 BK=64, split-K=4 ----------
// Double-buffered LDS, 2-deep register prefetch with COMPILE-TIME set/buffer
// parity (named sets va0/va1 — R6's va[p] dynamic index spilled to scratch).
__global__ __launch_bounds__(256, 2) void gemm_kernel(
    const _Float16* __restrict__ Ahs, const _Float16* __restrict__ Bw1,
    float* __restrict__ part) {
  __shared__ _Float16 As[2 * 128 * 64];
  __shared__ _Float16 Bs[2 * 128 * 64];

  const int bid = (int)blockIdx.x;
  const int m0 = (bid & 31) << 7;
  const int n0 = ((bid >> 5) & 3) << 7;
  const int ksp = bid >> 7;
  const int k0 = ksp << 11;   // * 2048
  float* outp = part + (size_t)ksp * ((size_t)B_ * GN);

  const int tid = (int)threadIdx.x;
  const int lane = tid & 63, w = tid >> 6;
  const int wm = w & 1, wn = w >> 1;
  const int lq = lane >> 4, lr = lane & 15;

  const _Float16* gA[4]; const _Float16* gB[4]; int lp[4];
#pragma unroll
  for (int j = 0; j < 4; ++j) {
    int p = tid + 256 * j;               // 0..1023
    int row = p >> 3, q = p & 7, cg = q ^ (row & 7);
    gA[j] = Ahs + (size_t)(m0 + row) * GK + k0 + cg * 8;
    gB[j] = Bw1 + (size_t)(n0 + row) * GK + k0 + cg * 8;
    lp[j] = p * 8;
  }

  int offA[4][2], offB[4][2];
#pragma unroll
  for (int mt = 0; mt < 4; ++mt)
#pragma unroll
    for (int ks = 0; ks < 2; ++ks) {
      int m = wm * 64 + mt * 16 + lr;
      offA[mt][ks] = m * 64 + (((lq + ks * 4) ^ (m & 7)) << 3);
      int n = wn * 64 + mt * 16 + lr;
      offB[mt][ks] = n * 64 + (((lq + ks * 4) ^ (n & 7)) << 3);
    }

  f32x4 acc[4][4];
#pragma unroll
  for (int mt = 0; mt < 4; ++mt)
#pragma unroll
    for (int nt = 0; nt < 4; ++nt) {
      acc[mt][nt][0] = 0.f; acc[mt][nt][1] = 0.f;
      acc[mt][nt][2] = 0.f; acc[mt][nt][3] = 0.f;
    }

  // preload k-chunks 0 (set0) and 1 (set1)
  half8 va0[4], vb0[4], va1[4], vb1[4];
#pragma unroll
  for (int j = 0; j < 4; ++j) {
    va0[j] = *(const half8*)gA[j];        vb0[j] = *(const half8*)gB[j];
    va1[j] = *(const half8*)(gA[j] + 64); vb1[j] = *(const half8*)(gB[j] + 64);
    gA[j] += 128; gB[j] += 128;
  }

#define GPHASE(SET, POFF, guard)                                               \
  do {                                                                         \
    _Pragma("unroll") for (int j = 0; j < 4; ++j) {                            \
      *(half8*)&As[(POFF) + lp[j]] = va##SET[j];                               \
      *(half8*)&Bs[(POFF) + lp[j]] = vb##SET[j];                               \
    }                                                                          \
    if (guard) {                                                               \
      _Pragma("unroll") for (int j = 0; j < 4; ++j) {                          \
        va##SET[j] = *(const half8*)gA[j];                                     \
        vb##SET[j] = *(const half8*)gB[j];                                     \
        gA[j] += 64; gB[j] += 64;                                              \
      }                                                                        \
    }                                                                          \
    ldsbar();                                                                  \
    half8 af[4][2], bf[4][2];                                                  \
    _Pragma("unroll") for (int mt = 0; mt < 4; ++mt)                           \
      _Pragma("unroll") for (int ks = 0; ks < 2; ++ks) {                       \
        af[mt][ks] = *(const half8*)&As[(POFF) + offA[mt][ks]];                \
        bf[mt][ks] = *(const half8*)&Bs[(POFF) + offB[mt][ks]];                \
      }                                                                        \
    _Pragma("unroll") for (int ks = 0; ks < 2; ++ks)                           \
      _Pragma("unroll") for (int mt = 0; mt < 4; ++mt)                         \
        _Pragma("unroll") for (int nt = 0; nt < 4; ++nt)                       \
          acc[mt][nt] = __builtin_amdgcn_mfma_f32_16x16x32_f16(                \
              af[mt][ks], bf[nt][ks], acc[mt][nt], 0, 0, 0);                   \
  } while (0)

  for (int it2 = 0; it2 < 16; ++it2) {
    const bool g = (it2 < 15);
    GPHASE(0, 0, g);
    GPHASE(1, 8192, g);
  }
#undef GPHASE

  // epilogue: C layout col=lr, row=lq*4+reg; plain stores to this split's buffer
#pragma unroll
  for (int mt = 0; mt < 4; ++mt)
#pragma unroll
    for (int nt = 0; nt < 4; ++nt) {
      int n = n0 + wn * 64 + nt * 16 + lr;
#pragma unroll
      for (int r = 0; r < 4; ++r) {
        int m = m0 + wm * 64 + mt * 16 + lq * 4 + r;
        outp[(size_t)m * GN + n] = acc[mt][nt][r];
      }
    }
}

// ---------- kernel 4: head — sum KSPLIT partials, bias, relu, dot W2 ----------
__global__ __launch_bounds__(256) void head_kernel(const float* __restrict__ part,
                                                   const float* __restrict__ b1,
                                                   const float* __restrict__ W2,
                                                   const float* __restrict__ b2,
                                                   float* __restrict__ out) {
  const int b = (int)(blockIdx.x * 4 + (threadIdx.x >> 6));
  const int l = (int)(threadIdx.x & 63);
  const size_t stride = (size_t)B_ * GN;
  const float4* b14 = (const float4*)b1;
  const float4* w4 = (const float4*)W2;
  float s = 0.0f;
#pragma unroll
  for (int p = 0; p < 2; ++p) {
    int i = p * 64 + l;
    float4 hv = ((const float4*)(part + (size_t)b * GN))[i];
#pragma unroll
    for (int sp = 1; sp < KSPLIT; ++sp) {
      float4 pv = ((const float4*)(part + sp * stride + (size_t)b * GN))[i];
      hv.x += pv.x; hv.y += pv.y; hv.z += pv.z; hv.w += pv.w;
    }
    float4 bv = b14[i], wv = w4[i];
    float t0 = fmaxf(hv.x + bv.x, 0.0f);
    float t1 = fmaxf(hv.y + bv.y, 0.0f);
    float t2 = fmaxf(hv.z + bv.z, 0.0f);
    float t3 = fmaxf(hv.w + bv.w, 0.0f);
    s = fmaf(t0, wv.x, s); s = fmaf(t1, wv.y, s);
    s = fmaf(t2, wv.z, s); s = fmaf(t3, wv.w, s);
  }
#pragma unroll
  for (int off = 32; off >= 1; off >>= 1) s += __shfl_xor(s, off);
  if (l == 0) out[b] = s + b2[0];
}

extern "C" void kernel_launch(void* const* d_in, const int* in_sizes, int n_in,
                              void* d_out, int out_size, void* d_ws, size_t ws_size,
                              hipStream_t stream) {
  const float* batch = (const float*)d_in[0];
  const float* W_ih = (const float*)d_in[1];
  const float* W_hh = (const float*)d_in[2];
  const float* b_ih = (const float*)d_in[3];
  const float* b_hh = (const float*)d_in[4];
  const float* W1 = (const float*)d_in[5];
  const float* b1 = (const float*)d_in[6];
  const float* W2 = (const float*)d_in[7];
  const float* b2 = (const float*)d_in[8];
  float* out = (float*)d_out;

  char* ws = (char*)d_ws;
  _Float16* hs = (_Float16*)ws;                         // 4096*8192*2 = 67108864 B
  _Float16* w1h = (_Float16*)(ws + 67108864);           // 512*8192*2  =  8388608 B
  float* part = (float*)(ws + 67108864 + 8388608);      // 4*4096*512*4 = 33554432 B

  cvtw1_kernel<<<4096, 256, 0, stream>>>(W1, (unsigned short*)w1h);
  lstm_kernel<<<256, 512, 0, stream>>>(batch, W_ih, W_hh, b_ih, b_hh, hs);
  gemm_kernel<<<512, 256, 0, stream>>>(hs, w1h, part);
  head_kernel<<<1024, 256, 0, stream>>>(part, b1, W2, b2, out);
}